// Round 11
// baseline (132.562 us; speedup 1.0000x reference)
//
#include <hip/hip_runtime.h>
#include <hip/hip_bf16.h>
#include <stdint.h>

constexpr int NUM_NODES = 120000;
constexpr int Tn = 10;
constexpr int Bb = 64, Rr = 4, Nn = 64, Cc = 64, Ii = 64;
constexpr int G = 8;            // sequences per block
constexpr int RSTR  = 147456;   // per-relation Wf stride (bf16 elems)
constexpr int OFF0  = 0;        // L0 w1   [tap2][ct4][ks4][lane64][8]
constexpr int OFF1  = 16384;    // L0 down [ct4][ks4][lane64][8]
constexpr int OFF2  = 24576;    // L0 w2   [tap2][ct4][ks2][lane64][8]
constexpr int OFFL0 = 32768;    // levels  14 x [tap2][ct4][ks2][lane64][8]

// LDS byte offsets. No X staging (level-0 reads emb directly).
// H1 aliases Y's dead tail (slots 6..9 unused after p3).
constexpr int OFF_Y  = 0;       // 10 slots x 1024 = 10240 (post-p1 writes stay < 6144)
constexpr int OFF_H1 = 6144;    // 4 slots  (6144..10240, inside Y tail)
constexpr int OFF_H0 = 10240;   // 6 slots  (10240..16384)
constexpr int OFF_H2 = 16384;   // 2 slots  (16384..18432)
constexpr int OFF_H3 = 18432;   // H3..H6 at +1024 each; dup-tails extend to 23552
constexpr int ZOFF   = 23552;   // 256B zero block
constexpr int SMEMB  = 23808;

typedef __attribute__((ext_vector_type(8))) short bf16x8;
typedef __attribute__((ext_vector_type(4))) float f32x4;
typedef __attribute__((ext_vector_type(4))) short s16x4;

__device__ __forceinline__ short f2bf(float f) {
  __hip_bfloat16 h = __float2bfloat16(f);
  return *reinterpret_cast<short*>(&h);
}
__device__ __forceinline__ float bf2f(short s) {
  union { unsigned int u; float f; } x;
  x.u = ((unsigned int)(unsigned short)s) << 16;
  return x.f;
}

// ---------------------------------------------------------------------------
// Bake weights into per-lane MFMA A-fragments (bf16). (verified rounds 3-10)
// ---------------------------------------------------------------------------
extern "C" __global__ void prep_kernel(const float* __restrict__ w1_0,
                                       const float* __restrict__ w2_0,
                                       const float* __restrict__ down_w,
                                       const float* __restrict__ w1s,
                                       const float* __restrict__ w2s,
                                       short* __restrict__ Wf) {
  int i0 = blockIdx.x * blockDim.x + threadIdx.x;
  int stride = gridDim.x * blockDim.x;
  for (int e = i0; e < Rr * RSTR; e += stride) {
    int r = e / RSTR, q = e - r * RSTR;
    float v;
    if (q < 16384) {
      int j = q & 7, lane = (q >> 3) & 63, ks = (q >> 9) & 3, ct = (q >> 11) & 3, tap = (q >> 13) & 1;
      int cout = ct * 16 + (lane & 15), cin = ks * 32 + (lane >> 4) * 8 + j;
      v = w1_0[((r * 64 + cout) * 128 + cin) * 2 + tap];
    } else if (q < 24576) {
      int q2 = q - 16384;
      int j = q2 & 7, lane = (q2 >> 3) & 63, ks = (q2 >> 9) & 3, ct = (q2 >> 11) & 3;
      int cout = ct * 16 + (lane & 15), cin = ks * 32 + (lane >> 4) * 8 + j;
      v = down_w[(r * 64 + cout) * 128 + cin];
    } else if (q < 32768) {
      int q2 = q - 24576;
      int j = q2 & 7, lane = (q2 >> 3) & 63, ks = (q2 >> 9) & 1, ct = (q2 >> 10) & 3, tap = (q2 >> 12) & 1;
      int cout = ct * 16 + (lane & 15), cin = ks * 32 + (lane >> 4) * 8 + j;
      v = w2_0[((r * 64 + cout) * 64 + cin) * 2 + tap];
    } else {
      int q2 = q - 32768;
      int lc = q2 >> 13;
      int l = lc >> 1, jw = lc & 1;
      int q3 = q2 & 8191;
      int j = q3 & 7, lane = (q3 >> 3) & 63, ks = (q3 >> 9) & 1, ct = (q3 >> 10) & 3, tap = (q3 >> 12) & 1;
      int cout = ct * 16 + (lane & 15), cin = ks * 32 + (lane >> 4) * 8 + j;
      const float* src = jw ? w2s : w1s;
      v = src[(((r * 7 + l) * 64 + cout) * 64 + cin) * 2 + tap];
    }
    Wf[e] = f2bf(v);
  }
}

// ---------------------------------------------------------------------------
// Level-0 conv: B-fragments loaded DIRECTLY from emb (f32 -> bf16 in regs).
// eo[t] = packed (t*NUM_NODES + row) element offset, 0xFFFFFFFF = invalid.
// Maps T1/T0 are constexpr at call sites -> eo[] indices fold to constants.
// ---------------------------------------------------------------------------
template <int NMT, int NTAP>
__device__ __forceinline__ void conv_gl(const float* __restrict__ emb,
                                        const unsigned int (&eo)[10],
                                        const short* __restrict__ wf1,
                                        const short* __restrict__ wf0,
                                        const float* __restrict__ bias,
                                        const int (&T1)[NMT * 2], const int (&T0)[NMT * 2],
                                        int lane, int ct, f32x4 (&acc)[NMT]) {
  const int hi = (lane & 15) >> 3;
  const int cin0 = (lane >> 4) * 8;
  float bv[4];
#pragma unroll
  for (int g = 0; g < 4; ++g) bv[g] = bias[ct * 16 + (lane >> 4) * 4 + g];
#pragma unroll
  for (int mt = 0; mt < NMT; ++mt) acc[mt] = (f32x4){bv[0], bv[1], bv[2], bv[3]};
  bf16x8 af1[4], af0[4];
#pragma unroll
  for (int ks = 0; ks < 4; ++ks)
    af1[ks] = *(const bf16x8*)(wf1 + ((ct * 4 + ks) * 64 + lane) * 8);
  if (NTAP == 2) {
#pragma unroll
    for (int ks = 0; ks < 4; ++ks)
      af0[ks] = *(const bf16x8*)(wf0 + ((ct * 4 + ks) * 64 + lane) * 8);
  }
#pragma unroll
  for (int mt = 0; mt < NMT; ++mt) {
    {
      unsigned int elo = (T1[2 * mt] >= 0) ? eo[(T1[2 * mt] < 0) ? 0 : T1[2 * mt]] : 0xFFFFFFFFu;
      unsigned int ehi = (T1[2 * mt + 1] >= 0) ? eo[(T1[2 * mt + 1] < 0) ? 0 : T1[2 * mt + 1]] : 0xFFFFFFFFu;
      unsigned int e = hi ? ehi : elo;
      bool val = (e != 0xFFFFFFFFu);
      const float* bp = emb + (size_t)(val ? e : 0u) * 128 + cin0;
#pragma unroll
      for (int ks = 0; ks < 4; ++ks) {
        bf16x8 bfrag = {0, 0, 0, 0, 0, 0, 0, 0};
        if (val) {
          f32x4 v0 = *(const f32x4*)(bp + ks * 32);
          f32x4 v1 = *(const f32x4*)(bp + ks * 32 + 4);
          bfrag[0] = f2bf(v0[0]); bfrag[1] = f2bf(v0[1]);
          bfrag[2] = f2bf(v0[2]); bfrag[3] = f2bf(v0[3]);
          bfrag[4] = f2bf(v1[0]); bfrag[5] = f2bf(v1[1]);
          bfrag[6] = f2bf(v1[2]); bfrag[7] = f2bf(v1[3]);
        }
        acc[mt] = __builtin_amdgcn_mfma_f32_16x16x32_bf16(af1[ks], bfrag, acc[mt], 0, 0, 0);
      }
    }
    if (NTAP == 2) {
      unsigned int elo = (T0[2 * mt] >= 0) ? eo[(T0[2 * mt] < 0) ? 0 : T0[2 * mt]] : 0xFFFFFFFFu;
      unsigned int ehi = (T0[2 * mt + 1] >= 0) ? eo[(T0[2 * mt + 1] < 0) ? 0 : T0[2 * mt + 1]] : 0xFFFFFFFFu;
      unsigned int e = hi ? ehi : elo;
      bool val = (e != 0xFFFFFFFFu);
      const float* bp = emb + (size_t)(val ? e : 0u) * 128 + cin0;
#pragma unroll
      for (int ks = 0; ks < 4; ++ks) {
        bf16x8 bfrag = {0, 0, 0, 0, 0, 0, 0, 0};
        if (val) {
          f32x4 v0 = *(const f32x4*)(bp + ks * 32);
          f32x4 v1 = *(const f32x4*)(bp + ks * 32 + 4);
          bfrag[0] = f2bf(v0[0]); bfrag[1] = f2bf(v0[1]);
          bfrag[2] = f2bf(v0[2]); bfrag[3] = f2bf(v0[3]);
          bfrag[4] = f2bf(v1[0]); bfrag[5] = f2bf(v1[1]);
          bfrag[6] = f2bf(v1[2]); bfrag[7] = f2bf(v1[3]);
        }
        acc[mt] = __builtin_amdgcn_mfma_f32_16x16x32_bf16(af0[ks], bfrag, acc[mt], 0, 0, 0);
      }
    }
  }
}

// ---------------------------------------------------------------------------
// Sparse-slot conv pass over LDS (KSN=2, ROWB=128 only now).
// ---------------------------------------------------------------------------
template <int KSN, int NMT, int NTAP, int ROWB>
__device__ __forceinline__ void conv_sp(const char* __restrict__ sm, int srcOff,
                                        const short* __restrict__ wf1,
                                        const short* __restrict__ wf0,
                                        const float* __restrict__ bias,
                                        const int (&T1)[NMT * 2], const int (&T0)[NMT * 2],
                                        int lane, int ct, f32x4 (&acc)[NMT]) {
  const int c16 = (lane >> 4) * 16;
  const int seq = lane & 7;
  const int hi = (lane & 15) >> 3;
  const int sw = seq << 4;
  float bv[4];
#pragma unroll
  for (int g = 0; g < 4; ++g) bv[g] = bias[ct * 16 + (lane >> 4) * 4 + g];
#pragma unroll
  for (int mt = 0; mt < NMT; ++mt) acc[mt] = (f32x4){bv[0], bv[1], bv[2], bv[3]};
  bf16x8 af1[KSN], af0[KSN];
#pragma unroll
  for (int ks = 0; ks < KSN; ++ks)
    af1[ks] = *(const bf16x8*)(wf1 + ((ct * KSN + ks) * 64 + lane) * 8);
  if (NTAP == 2) {
#pragma unroll
    for (int ks = 0; ks < KSN; ++ks)
      af0[ks] = *(const bf16x8*)(wf0 + ((ct * KSN + ks) * 64 + lane) * 8);
  }
#pragma unroll
  for (int mt = 0; mt < NMT; ++mt) {
    int s1 = hi ? T1[2 * mt + 1] : T1[2 * mt];
    const char* p1 = sm + ((s1 < 0) ? ZOFF : srcOff + (s1 * 8 + seq) * ROWB);
#pragma unroll
    for (int ks = 0; ks < KSN; ++ks) {
      bf16x8 b = *(const bf16x8*)(p1 + ((ks * 64 + c16) ^ sw));
      acc[mt] = __builtin_amdgcn_mfma_f32_16x16x32_bf16(af1[ks], b, acc[mt], 0, 0, 0);
    }
    if (NTAP == 2) {
      int s0 = hi ? T0[2 * mt + 1] : T0[2 * mt];
      const char* p0 = sm + ((s0 < 0) ? ZOFF : srcOff + (s0 * 8 + seq) * ROWB);
#pragma unroll
      for (int ks = 0; ks < KSN; ++ks) {
        bf16x8 b = *(const bf16x8*)(p0 + ((ks * 64 + c16) ^ sw));
        acc[mt] = __builtin_amdgcn_mfma_f32_16x16x32_bf16(af0[ks], b, acc[mt], 0, 0, 0);
      }
    }
  }
}

template <int NMT>
__device__ __forceinline__ void store_sp(char* __restrict__ sm, int dstOff, int lane,
                                         int ct, const f32x4 (&v)[NMT]) {
  const int co = ct * 32 + (lane >> 4) * 8;
#pragma unroll
  for (int mt = 0; mt < NMT; ++mt) {
    int oc = 16 * mt + (lane & 15);
    s16x4 p;
#pragma unroll
    for (int g = 0; g < 4; ++g) p[g] = f2bf(v[mt][g]);
    *(s16x4*)(sm + dstOff + oc * 128 + (co ^ ((oc & 7) << 4))) = p;
  }
}

#define RELU_ALL(A, N)                                        \
  _Pragma("unroll") for (int _t = 0; _t < N; ++_t)            \
      _Pragma("unroll") for (int _g = 0; _g < 4; ++_g)        \
          A[_t][_g] = fmaxf(A[_t][_g], 0.f);

// residual: h = relu(relu(acc) + H_prev(bf16 from LDS))
template <int NMT>
__device__ __forceinline__ void resid_sp(const char* __restrict__ sm, int prevOff,
                                         const int (&R)[NMT * 2], int lane, int ct,
                                         f32x4 (&a)[NMT]) {
  const int co = ct * 32 + (lane >> 4) * 8;
  const int seq = lane & 7;
  const int hi = (lane & 15) >> 3;
  const int sw = seq << 4;
#pragma unroll
  for (int mt = 0; mt < NMT; ++mt) {
    int rs = hi ? R[2 * mt + 1] : R[2 * mt];
    const char* p = sm + ((rs < 0) ? ZOFF : prevOff + (rs * 8 + seq) * 128);
    s16x4 q = *(const s16x4*)(p + (co ^ sw));
#pragma unroll
    for (int g = 0; g < 4; ++g)
      a[mt][g] = fmaxf(fmaxf(a[mt][g], 0.f) + bf2f(q[g]), 0.f);
  }
}

// ---------------------------------------------------------------------------
// Main: direct-global level-0 + temporally-sparse TCN (44 cols/seq).
// Block = 256 thr = 4 waves (wave = cout-tile of 16), 8 valid sequences.
// ---------------------------------------------------------------------------
extern "C" __global__ void __launch_bounds__(256, 4)
tcn_mfma(const float* __restrict__ emb, const int* __restrict__ align_,
         const int* __restrict__ nidx, const int* __restrict__ nmask,
         const float* __restrict__ b1_0, const float* __restrict__ b2_0,
         const float* __restrict__ down_b, const float* __restrict__ b1s,
         const float* __restrict__ b2s, const short* __restrict__ Wf,
         float* __restrict__ P) {
  __shared__ char sm[SMEMB];
  __shared__ int rowid[80];
  __shared__ float mkv[G];
  __shared__ int mapg[G];
  __shared__ int totv;

  const int tid = threadIdx.x;
  const int lane = tid & 63, ct = tid >> 6;
  const int blk = blockIdx.x;
  const int r = blk >> 9;
  const int blkr = blk & 511;
  const int b = blkr >> 3, chunk = blkr & 7;

  // ---- ballot compaction of this (b,r)'s valid neighbors ----
  if (tid < 64) {
    int n = tid;
    int msk = nmask[(b * Rr + r) * Nn + n];
    unsigned long long bal = __ballot(msk != 0);
    if (tid < G) mapg[tid] = -1;
    if (tid == 0) totv = (int)__popcll(bal);
    int rank = (int)__popcll(bal & ((1ull << n) - 1ull));
    if (msk != 0 && rank >= chunk * G && rank < chunk * G + G)
      mapg[rank - chunk * G] = n;
  }
  if (tid >= 192 && tid < 224) *(uint64_t*)(sm + ZOFF + (tid - 192) * 8) = 0;
  __syncthreads();
  if (chunk * G >= totv) {           // inactive block: zero partial, exit
    if (tid < 64) P[((r * Bb + b) * 8 + chunk) * 64 + tid] = 0.f;
    return;
  }

  // col = t*8 + seq  (slot-major packing)
  if (tid < 80) {
    int t = tid >> 3, seq = tid & 7;
    int n2 = mapg[seq];
    int s = -1;
    if (n2 >= 0) {
      int ent = nidx[(b * Rr + r) * Nn + n2];
      s = align_[ent * Tn + t];
    }
    rowid[tid] = (n2 >= 0 && s >= 0) ? s : -1;
    if (t == 0) mkv[seq] = (n2 >= 0) ? 1.0f : 0.0f;
  }
  __syncthreads();

  // per-lane packed element offsets for the 10 X columns of this lane's seq
  unsigned int eo[10];
  {
    const int seq = lane & 7;
#pragma unroll
    for (int t = 0; t < 10; ++t) {
      int rv = rowid[t * 8 + seq];
      eo[t] = (rv >= 0) ? (unsigned int)(t * NUM_NODES + rv) : 0xFFFFFFFFu;
    }
  }

  const short* wr = Wf + r * RSTR;

  // ---- pass1: Y0 = relu(conv1_0(X)), all t  (X direct from global) ----
  {
    static constexpr int T1[10] = {0, 1, 2, 3, 4, 5, 6, 7, 8, 9};
    static constexpr int T0[10] = {-1, 0, 1, 2, 3, 4, 5, 6, 7, 8};
    f32x4 a[5];
    conv_gl<5, 2>(emb, eo, wr + OFF0 + 8192, wr + OFF0, b1_0 + r * 64,
                  T1, T0, lane, ct, a);
    RELU_ALL(a, 5)
    store_sp<5>(sm, OFF_Y, lane, ct, a);
  }
  // ---- pass2: down(X) at odd t, carried in regs (X direct from global) ----
  f32x4 accD[3];
  {
    static constexpr int TD[6] = {1, 3, 5, 7, 9, 9};
    conv_gl<3, 1>(emb, eo, wr + OFF1, wr + OFF1, down_b + r * 64,
                  TD, TD, lane, ct, accD);
  }
  __syncthreads();
  // ---- pass3: H0 = relu(relu(conv2_0(Y0)) + down) at odd t ----
  {
    constexpr int T1[6] = {1, 3, 5, 7, 9, 9};
    constexpr int T0[6] = {0, 2, 4, 6, 8, 8};
    f32x4 a[3];
    conv_sp<2, 3, 2, 128>(sm, OFF_Y, wr + OFF2 + 4096, wr + OFF2, b2_0 + r * 64,
                          T1, T0, lane, ct, a);
#pragma unroll
    for (int mt = 0; mt < 3; ++mt)
#pragma unroll
      for (int g = 0; g < 4; ++g)
        a[mt][g] = fmaxf(fmaxf(a[mt][g], 0.f) + accD[mt][g], 0.f);
    store_sp<3>(sm, OFF_H0, lane, ct, a);
  }
  __syncthreads();
  // ---- level 1 (d=2): Y1 at H0-slots; H1 at [1,5,9] ----
  {
    constexpr int T1[6] = {0, 1, 2, 3, 4, 4};
    constexpr int T0[6] = {-1, 0, 1, 2, 3, 3};
    f32x4 a[3];
    const short* wb = wr + OFFL0;
    conv_sp<2, 3, 2, 128>(sm, OFF_H0, wb + 4096, wb, b1s + (r * 7 + 0) * 64,
                          T1, T0, lane, ct, a);
    RELU_ALL(a, 3)
    store_sp<3>(sm, OFF_Y, lane, ct, a);
  }
  __syncthreads();
  {
    constexpr int T1[4] = {0, 2, 4, 4};
    constexpr int T0[4] = {-1, 1, 3, 3};
    constexpr int R[4] = {0, 2, 4, 4};
    f32x4 a[2];
    const short* wb = wr + OFFL0 + 8192;
    conv_sp<2, 2, 2, 128>(sm, OFF_Y, wb + 4096, wb, b2s + (r * 7 + 0) * 64,
                          T1, T0, lane, ct, a);
    resid_sp<2>(sm, OFF_H0, R, lane, ct, a);
    store_sp<2>(sm, OFF_H1, lane, ct, a);
  }
  __syncthreads();
  // ---- level 2 (d=4): Y2 at [1,5,9]; H2 at [1,9] ----
  {
    constexpr int T1[4] = {0, 1, 2, 2};
    constexpr int T0[4] = {-1, 0, 1, 1};
    f32x4 a[2];
    const short* wb = wr + OFFL0 + 16384;
    conv_sp<2, 2, 2, 128>(sm, OFF_H1, wb + 4096, wb, b1s + (r * 7 + 1) * 64,
                          T1, T0, lane, ct, a);
    RELU_ALL(a, 2)
    store_sp<2>(sm, OFF_Y, lane, ct, a);
  }
  __syncthreads();
  {
    constexpr int T1[2] = {0, 2};
    constexpr int T0[2] = {-1, 1};
    constexpr int R[2] = {0, 2};
    f32x4 a[1];
    const short* wb = wr + OFFL0 + 16384 + 8192;
    conv_sp<2, 1, 2, 128>(sm, OFF_Y, wb + 4096, wb, b2s + (r * 7 + 1) * 64,
                          T1, T0, lane, ct, a);
    resid_sp<1>(sm, OFF_H1, R, lane, ct, a);
    store_sp<1>(sm, OFF_H2, lane, ct, a);
  }
  __syncthreads();
  // ---- level 3 (d=8): Y3 at [1,9]; H3 at [9] ----
  {
    constexpr int T1[2] = {0, 1};
    constexpr int T0[2] = {-1, 0};
    f32x4 a[1];
    const short* wb = wr + OFFL0 + 32768;
    conv_sp<2, 1, 2, 128>(sm, OFF_H2, wb + 4096, wb, b1s + (r * 7 + 2) * 64,
                          T1, T0, lane, ct, a);
    RELU_ALL(a, 1)
    store_sp<1>(sm, OFF_Y, lane, ct, a);
  }
  __syncthreads();
  {
    constexpr int T1[2] = {1, 1};
    constexpr int T0[2] = {0, 0};
    constexpr int R[2] = {1, 1};
    f32x4 a[1];
    const short* wb = wr + OFFL0 + 32768 + 8192;
    conv_sp<2, 1, 2, 128>(sm, OFF_Y, wb + 4096, wb, b2s + (r * 7 + 2) * 64,
                          T1, T0, lane, ct, a);
    resid_sp<1>(sm, OFF_H2, R, lane, ct, a);
    store_sp<1>(sm, OFF_H3, lane, ct, a);
  }
  __syncthreads();

  // ---- levels 4..7 (d>=16, single tap, single slot t=9) ----
  f32x4 hfin[1];
  static constexpr int TA[2] = {0, 0};
#pragma unroll 1
  for (int li = 0; li < 4; ++li) {
    const short* base = wr + OFFL0 + (3 + li) * 16384;
    const int prevOff = OFF_H3 + li * 1024;
    {
      f32x4 a[1];
      conv_sp<2, 1, 1, 128>(sm, prevOff, base + 4096, base + 4096,
                            b1s + (r * 7 + 3 + li) * 64, TA, TA, lane, ct, a);
      RELU_ALL(a, 1)
      store_sp<1>(sm, OFF_Y, lane, ct, a);
    }
    __syncthreads();
    {
      f32x4 a[1];
      conv_sp<2, 1, 1, 128>(sm, OFF_Y, base + 8192 + 4096, base + 8192 + 4096,
                            b2s + (r * 7 + 3 + li) * 64, TA, TA, lane, ct, a);
      resid_sp<1>(sm, prevOff, TA, lane, ct, a);
      if (li < 3) store_sp<1>(sm, prevOff + 1024, lane, ct, a);
      hfin[0] = a[0];
    }
    __syncthreads();
  }

  // ---- epilogue: mask + reduce over 8 sequences (lanes 0-7 of each group) ----
  float mk = ((lane & 15) < 8) ? mkv[lane & 7] : 0.f;
  float s0 = hfin[0][0] * mk, s1 = hfin[0][1] * mk, s2 = hfin[0][2] * mk, s3 = hfin[0][3] * mk;
#pragma unroll
  for (int m2 = 1; m2 <= 4; m2 <<= 1) {
    s0 += __shfl_xor(s0, m2);
    s1 += __shfl_xor(s1, m2);
    s2 += __shfl_xor(s2, m2);
    s3 += __shfl_xor(s3, m2);
  }
  if ((lane & 15) == 0) {
    int base = ((r * Bb + b) * 8 + chunk) * 64 + ct * 16 + (lane >> 4) * 4;
    P[base + 0] = s0;
    P[base + 1] = s1;
    P[base + 2] = s2;
    P[base + 3] = s3;
  }
}

// ---------------------------------------------------------------------------
// out[b][i] = sum_r sum_c (sum_p P[r][b][p][c]) * rel_w[r][c][i]
// ---------------------------------------------------------------------------
extern "C" __global__ void reduce_kernel(const float* __restrict__ P,
                                         const float* __restrict__ rel_w,
                                         float* __restrict__ out) {
  __shared__ float Sl[Rr * Cc];
  int b = blockIdx.x, i = threadIdx.x;
  for (int idx = i; idx < Rr * Cc; idx += 64) {
    int rr = idx >> 6, cc = idx & 63;
    float s = 0.f;
    for (int p = 0; p < 8; ++p) s += P[((rr * Bb + b) * 8 + p) * 64 + cc];
    Sl[idx] = s;
  }
  __syncthreads();
  float acc = 0.f;
  for (int r = 0; r < Rr; ++r)
#pragma unroll
    for (int cc = 0; cc < 64; ++cc)
      acc += Sl[r * Cc + cc] * rel_w[(r * Cc + cc) * Ii + i];
  out[b * Ii + i] = acc;
}

// ---------------------------------------------------------------------------
extern "C" void kernel_launch(void* const* d_in, const int* in_sizes, int n_in,
                              void* d_out, int out_size, void* d_ws, size_t ws_size,
                              hipStream_t stream) {
  const float* emb    = (const float*)d_in[0];
  const float* w1_0   = (const float*)d_in[1];
  const float* b1_0   = (const float*)d_in[2];
  const float* w2_0   = (const float*)d_in[3];
  const float* b2_0   = (const float*)d_in[4];
  const float* down_w = (const float*)d_in[5];
  const float* down_b = (const float*)d_in[6];
  const float* w1s    = (const float*)d_in[7];
  const float* b1s    = (const float*)d_in[8];
  const float* w2s    = (const float*)d_in[9];
  const float* b2s    = (const float*)d_in[10];
  const float* rel_w  = (const float*)d_in[11];
  const int* align_   = (const int*)d_in[12];
  const int* nidx     = (const int*)d_in[13];
  const int* nmask    = (const int*)d_in[14];

  float* P  = (float*)d_ws;                       // 4*64*8*64 f32 = 512 KB
  short* Wf = (short*)((char*)d_ws + 524288);     // 589824 bf16 = 1.15 MB

  prep_kernel<<<768, 256, 0, stream>>>(w1_0, w2_0, down_w, w1s, w2s, Wf);
  tcn_mfma<<<2048, 256, 0, stream>>>(emb, align_, nidx, nmask, b1_0, b2_0, down_b,
                                     b1s, b2s, Wf, P);
  reduce_kernel<<<Bb, Cc, 0, stream>>>(P, rel_w, (float*)d_out);
}

// Round 12
// 65.307 us; speedup vs baseline: 2.0298x; 2.0298x over previous
//
#include <hip/hip_runtime.h>
#include <hip/hip_bf16.h>
#include <stdint.h>

constexpr int NUM_NODES = 120000;
constexpr int Tn = 10;
constexpr int Bb = 64, Rr = 4, Nn = 64, Cc = 64, Ii = 64;
constexpr int G = 8;            // sequences per block
constexpr int RSTR  = 147456;   // per-relation Wf stride (bf16 elems)
constexpr int OFF0  = 0;        // L0 w1   [tap2][ct4][ks4][lane64][8]
constexpr int OFF1  = 16384;    // L0 down [ct4][ks4][lane64][8]
constexpr int OFF2  = 24576;    // L0 w2   [tap2][ct4][ks2][lane64][8]
constexpr int OFFL0 = 32768;    // levels  14 x [tap2][ct4][ks2][lane64][8]

// LDS byte offsets (H-chain aliases the dead X region) — r10 layout
constexpr int OFF_X  = 0;       // 80 cols x 256B = 20480
constexpr int OFF_H0 = 0;       // 5 slots x 1024 (valid after level 0)
constexpr int OFF_H1 = 6144;    // ~4 slots
constexpr int OFF_H2 = 10240;   // 2 slots
constexpr int OFF_H3 = 12288;   // H3..H6 at +1024 each
constexpr int OFF_Y  = 20480;   // 10 slots x 1024
constexpr int ZOFF   = 30720;   // 256B zero block
constexpr int SMEMB  = 30976;

typedef __attribute__((ext_vector_type(8))) short bf16x8;
typedef __attribute__((ext_vector_type(4))) float f32x4;
typedef __attribute__((ext_vector_type(4))) short s16x4;

__device__ __forceinline__ short f2bf(float f) {
  __hip_bfloat16 h = __float2bfloat16(f);
  return *reinterpret_cast<short*>(&h);
}
__device__ __forceinline__ float bf2f(short s) {
  union { unsigned int u; float f; } x;
  x.u = ((unsigned int)(unsigned short)s) << 16;
  return x.f;
}

// ---------------------------------------------------------------------------
// Bake weights into per-lane MFMA A-fragments (bf16). (verified rounds 3-11)
// ---------------------------------------------------------------------------
extern "C" __global__ void prep_kernel(const float* __restrict__ w1_0,
                                       const float* __restrict__ w2_0,
                                       const float* __restrict__ down_w,
                                       const float* __restrict__ w1s,
                                       const float* __restrict__ w2s,
                                       short* __restrict__ Wf) {
  int i0 = blockIdx.x * blockDim.x + threadIdx.x;
  int stride = gridDim.x * blockDim.x;
  for (int e = i0; e < Rr * RSTR; e += stride) {
    int r = e / RSTR, q = e - r * RSTR;
    float v;
    if (q < 16384) {
      int j = q & 7, lane = (q >> 3) & 63, ks = (q >> 9) & 3, ct = (q >> 11) & 3, tap = (q >> 13) & 1;
      int cout = ct * 16 + (lane & 15), cin = ks * 32 + (lane >> 4) * 8 + j;
      v = w1_0[((r * 64 + cout) * 128 + cin) * 2 + tap];
    } else if (q < 24576) {
      int q2 = q - 16384;
      int j = q2 & 7, lane = (q2 >> 3) & 63, ks = (q2 >> 9) & 3, ct = (q2 >> 11) & 3;
      int cout = ct * 16 + (lane & 15), cin = ks * 32 + (lane >> 4) * 8 + j;
      v = down_w[(r * 64 + cout) * 128 + cin];
    } else if (q < 32768) {
      int q2 = q - 24576;
      int j = q2 & 7, lane = (q2 >> 3) & 63, ks = (q2 >> 9) & 1, ct = (q2 >> 10) & 3, tap = (q2 >> 12) & 1;
      int cout = ct * 16 + (lane & 15), cin = ks * 32 + (lane >> 4) * 8 + j;
      v = w2_0[((r * 64 + cout) * 64 + cin) * 2 + tap];
    } else {
      int q2 = q - 32768;
      int lc = q2 >> 13;
      int l = lc >> 1, jw = lc & 1;
      int q3 = q2 & 8191;
      int j = q3 & 7, lane = (q3 >> 3) & 63, ks = (q3 >> 9) & 1, ct = (q3 >> 10) & 3, tap = (q3 >> 12) & 1;
      int cout = ct * 16 + (lane & 15), cin = ks * 32 + (lane >> 4) * 8 + j;
      const float* src = jw ? w2s : w1s;
      v = src[(((r * 7 + l) * 64 + cout) * 64 + cin) * 2 + tap];
    }
    Wf[e] = f2bf(v);
  }
}

// ---------------------------------------------------------------------------
// Paired-cout conv pass. wave = (cp, h): computes couts {2cp*16.., (2cp+1)*16..}
// over tiles [MT0, MT0+NL). Each LDS B-read feeds TWO MFMAs.
// ks-outer order (register-light; r9-validated numerics).
// ---------------------------------------------------------------------------
template <int KSN, int MT0, int NL, int NTAP, int ROWB, int NA>
__device__ __forceinline__ void conv_pp(const char* __restrict__ sm, int srcOff,
                                        const short* __restrict__ wf1,
                                        const short* __restrict__ wf0,
                                        const float* __restrict__ bias,
                                        const int (&T1)[NA], const int (&T0)[NA],
                                        int lane, int cp, f32x4 (&acc)[NL][2]) {
  const int c16 = (lane >> 4) * 16;
  const int seq = lane & 7;
  const int hi = (lane & 15) >> 3;
  const int sw = seq << 4;
#pragma unroll
  for (int i = 0; i < 2; ++i) {
    float b0 = bias[(2 * cp + i) * 16 + (lane >> 4) * 4 + 0];
    float b1 = bias[(2 * cp + i) * 16 + (lane >> 4) * 4 + 1];
    float b2 = bias[(2 * cp + i) * 16 + (lane >> 4) * 4 + 2];
    float b3 = bias[(2 * cp + i) * 16 + (lane >> 4) * 4 + 3];
#pragma unroll
    for (int mt = 0; mt < NL; ++mt) acc[mt][i] = (f32x4){b0, b1, b2, b3};
  }
#pragma unroll
  for (int ks = 0; ks < KSN; ++ks) {
    bf16x8 a1[2], a0[2];
#pragma unroll
    for (int i = 0; i < 2; ++i)
      a1[i] = *(const bf16x8*)(wf1 + (((2 * cp + i) * KSN + ks) * 64 + lane) * 8);
    if (NTAP == 2) {
#pragma unroll
      for (int i = 0; i < 2; ++i)
        a0[i] = *(const bf16x8*)(wf0 + (((2 * cp + i) * KSN + ks) * 64 + lane) * 8);
    }
#pragma unroll
    for (int mt = 0; mt < NL; ++mt) {
      int s1 = hi ? T1[2 * (MT0 + mt) + 1] : T1[2 * (MT0 + mt)];
      const char* p1 = sm + ((s1 < 0) ? ZOFF : srcOff + (s1 * 8 + seq) * ROWB);
      bf16x8 b = *(const bf16x8*)(p1 + ((ks * 64 + c16) ^ sw));
      acc[mt][0] = __builtin_amdgcn_mfma_f32_16x16x32_bf16(a1[0], b, acc[mt][0], 0, 0, 0);
      acc[mt][1] = __builtin_amdgcn_mfma_f32_16x16x32_bf16(a1[1], b, acc[mt][1], 0, 0, 0);
      if (NTAP == 2) {
        int s0 = hi ? T0[2 * (MT0 + mt) + 1] : T0[2 * (MT0 + mt)];
        const char* p0 = sm + ((s0 < 0) ? ZOFF : srcOff + (s0 * 8 + seq) * ROWB);
        bf16x8 b0v = *(const bf16x8*)(p0 + ((ks * 64 + c16) ^ sw));
        acc[mt][0] = __builtin_amdgcn_mfma_f32_16x16x32_bf16(a0[0], b0v, acc[mt][0], 0, 0, 0);
        acc[mt][1] = __builtin_amdgcn_mfma_f32_16x16x32_bf16(a0[1], b0v, acc[mt][1], 0, 0, 0);
      }
    }
  }
}

template <int MT0, int NL>
__device__ __forceinline__ void store_pp(char* __restrict__ sm, int dstOff, int lane,
                                         int cp, const f32x4 (&v)[NL][2]) {
  const int sw = (lane & 7) << 4;
#pragma unroll
  for (int mt = 0; mt < NL; ++mt) {
    int oc = 16 * (MT0 + mt) + (lane & 15);
#pragma unroll
    for (int i = 0; i < 2; ++i) {
      int co = (2 * cp + i) * 32 + (lane >> 4) * 8;
      s16x4 p;
#pragma unroll
      for (int g = 0; g < 4; ++g) p[g] = f2bf(v[mt][i][g]);
      *(s16x4*)(sm + dstOff + oc * 128 + (co ^ sw)) = p;
    }
  }
}

#define RELU_PP(A, N)                                         \
  _Pragma("unroll") for (int _t = 0; _t < N; ++_t)            \
      _Pragma("unroll") for (int _i = 0; _i < 2; ++_i)        \
          _Pragma("unroll") for (int _g = 0; _g < 4; ++_g)    \
              A[_t][_i][_g] = fmaxf(A[_t][_i][_g], 0.f);

template <int MT0, int NL, int NA>
__device__ __forceinline__ void resid_pp(const char* __restrict__ sm, int prevOff,
                                         const int (&R)[NA], int lane, int cp,
                                         f32x4 (&a)[NL][2]) {
  const int seq = lane & 7;
  const int hi = (lane & 15) >> 3;
  const int sw = seq << 4;
#pragma unroll
  for (int mt = 0; mt < NL; ++mt) {
    int rs = hi ? R[2 * (MT0 + mt) + 1] : R[2 * (MT0 + mt)];
    const char* p = sm + ((rs < 0) ? ZOFF : prevOff + (rs * 8 + seq) * 128);
#pragma unroll
    for (int i = 0; i < 2; ++i) {
      int co = (2 * cp + i) * 32 + (lane >> 4) * 8;
      s16x4 q = *(const s16x4*)(p + (co ^ sw));
#pragma unroll
      for (int g = 0; g < 4; ++g)
        a[mt][i][g] = fmaxf(fmaxf(a[mt][i][g], 0.f) + bf2f(q[g]), 0.f);
    }
  }
}

// conv + relu + store
template <int KSN, int MT0, int NL, int NTAP, int ROWB, int NA>
__device__ __forceinline__ void pass_crs(char* __restrict__ sm, int srcOff, int dstOff,
                                         const short* __restrict__ wf1,
                                         const short* __restrict__ wf0,
                                         const float* __restrict__ bias,
                                         const int (&T1)[NA], const int (&T0)[NA],
                                         int lane, int cp) {
  f32x4 a[NL][2];
  conv_pp<KSN, MT0, NL, NTAP, ROWB>(sm, srcOff, wf1, wf0, bias, T1, T0, lane, cp, a);
  RELU_PP(a, NL)
  store_pp<MT0, NL>(sm, dstOff, lane, cp, a);
}

// conv + resid + store
template <int KSN, int MT0, int NL, int NTAP, int ROWB, int NA>
__device__ __forceinline__ void pass_crr(char* __restrict__ sm, int srcOff, int prevOff,
                                         int dstOff, const short* __restrict__ wf1,
                                         const short* __restrict__ wf0,
                                         const float* __restrict__ bias,
                                         const int (&T1)[NA], const int (&T0)[NA],
                                         const int (&R)[NA], int lane, int cp) {
  f32x4 a[NL][2];
  conv_pp<KSN, MT0, NL, NTAP, ROWB>(sm, srcOff, wf1, wf0, bias, T1, T0, lane, cp, a);
  resid_pp<MT0, NL>(sm, prevOff, R, lane, cp, a);
  store_pp<MT0, NL>(sm, dstOff, lane, cp, a);
}

// ---------------------------------------------------------------------------
// Main: gather + temporally-sparse TCN; waves = (cout-pair cp, tile-half h).
// Block = 256 thr, 8 valid sequences, grid = 2048.
// ---------------------------------------------------------------------------
extern "C" __global__ void __launch_bounds__(256, 4)
tcn_mfma(const float* __restrict__ emb, const int* __restrict__ align_,
         const int* __restrict__ nidx, const int* __restrict__ nmask,
         const float* __restrict__ b1_0, const float* __restrict__ b2_0,
         const float* __restrict__ down_b, const float* __restrict__ b1s,
         const float* __restrict__ b2s, const short* __restrict__ Wf,
         float* __restrict__ P) {
  __shared__ char sm[SMEMB];
  __shared__ int rowid[80];
  __shared__ float mkv[G];
  __shared__ int mapg[G];
  __shared__ int totv;

  const int tid = threadIdx.x;
  const int lane = tid & 63, wave = tid >> 6;
  const int cp = wave & 1, h = wave >> 1;
  const int blk = blockIdx.x;
  const int r = blk >> 9;
  const int blkr = blk & 511;
  const int b = blkr >> 3, chunk = blkr & 7;

  // ---- ballot compaction of this (b,r)'s valid neighbors ----
  if (tid < 64) {
    int n = tid;
    int msk = nmask[(b * Rr + r) * Nn + n];
    unsigned long long bal = __ballot(msk != 0);
    if (tid < G) mapg[tid] = -1;
    if (tid == 0) totv = (int)__popcll(bal);
    int rank = (int)__popcll(bal & ((1ull << n) - 1ull));
    if (msk != 0 && rank >= chunk * G && rank < chunk * G + G)
      mapg[rank - chunk * G] = n;
  }
  if (tid >= 192 && tid < 224) *(uint64_t*)(sm + ZOFF + (tid - 192) * 8) = 0;
  __syncthreads();
  if (chunk * G >= totv) {           // inactive block: zero partial, exit
    if (tid < 64) P[((r * Bb + b) * 8 + chunk) * 64 + tid] = 0.f;
    return;
  }

  // col = t*8 + seq  (slot-major packing)
  if (tid < 80) {
    int t = tid >> 3, seq = tid & 7;
    int n2 = mapg[seq];
    int s = -1;
    if (n2 >= 0) {
      int ent = nidx[(b * Rr + r) * Nn + n2];
      s = align_[ent * Tn + t];
    }
    rowid[tid] = (n2 >= 0 && s >= 0) ? s : -1;
    if (t == 0) mkv[seq] = (n2 >= 0) ? 1.0f : 0.0f;
  }
  __syncthreads();

  // gather: 80 cols x 128 d, f32 -> bf16, b128 swizzled LDS writes
#pragma unroll
  for (int it = 0; it < 5; ++it) {
    int idx = tid + it * 256;
    int col = idx >> 4, d8 = idx & 15;
    int row = rowid[col];
    int t = col >> 3;
    bf16x8 p = {0, 0, 0, 0, 0, 0, 0, 0};
    if (row >= 0) {
      const float* src = emb + ((size_t)t * NUM_NODES + row) * 128 + d8 * 8;
      const float4 v0 = *(const float4*)(src);
      const float4 v1 = *(const float4*)(src + 4);
      p[0] = f2bf(v0.x); p[1] = f2bf(v0.y); p[2] = f2bf(v0.z); p[3] = f2bf(v0.w);
      p[4] = f2bf(v1.x); p[5] = f2bf(v1.y); p[6] = f2bf(v1.z); p[7] = f2bf(v1.w);
    }
    *(bf16x8*)(sm + OFF_X + col * 256 + ((d8 * 16) ^ ((col & 7) << 4))) = p;
  }
  __syncthreads();

  const short* wr = Wf + r * RSTR;

  // ---- maps (identical to r10, verified) ----
  static constexpr int T1p1[10] = {0, 1, 2, 3, 4, 5, 6, 7, 8, 9};
  static constexpr int T0p1[10] = {-1, 0, 1, 2, 3, 4, 5, 6, 7, 8};
  static constexpr int TDp2[6] = {1, 3, 5, 7, 9, 9};
  static constexpr int T1p3[6] = {1, 3, 5, 7, 9, 9};
  static constexpr int T0p3[6] = {0, 2, 4, 6, 8, 8};
  static constexpr int T1L1a[6] = {0, 1, 2, 3, 4, 4};
  static constexpr int T0L1a[6] = {-1, 0, 1, 2, 3, 3};
  static constexpr int T1L1b[4] = {0, 2, 4, 4};
  static constexpr int T0L1b[4] = {-1, 1, 3, 3};
  static constexpr int RL1b[4] = {0, 2, 4, 4};
  static constexpr int T1L2a[4] = {0, 1, 2, 2};
  static constexpr int T0L2a[4] = {-1, 0, 1, 1};
  static constexpr int T1L2b[2] = {0, 2};
  static constexpr int T0L2b[2] = {-1, 1};
  static constexpr int RL2b[2] = {0, 2};
  static constexpr int T1L3a[2] = {0, 1};
  static constexpr int T0L3a[2] = {-1, 0};
  static constexpr int T1L3b[2] = {1, 1};
  static constexpr int T0L3b[2] = {0, 0};
  static constexpr int RL3b[2] = {1, 1};
  static constexpr int TA[2] = {0, 0};

  // ---- p1 + p2 (read X; no barrier between) ----
  f32x4 accD[2][2];
  if (h == 0) {
    pass_crs<4, 0, 3, 2, 256>(sm, OFF_X, OFF_Y, wr + OFF0 + 8192, wr + OFF0,
                              b1_0 + r * 64, T1p1, T0p1, lane, cp);
    f32x4 aD[2][2];
    conv_pp<4, 0, 2, 1, 256>(sm, OFF_X, wr + OFF1, wr + OFF1, down_b + r * 64,
                             TDp2, TDp2, lane, cp, aD);
#pragma unroll
    for (int mt = 0; mt < 2; ++mt)
#pragma unroll
      for (int i = 0; i < 2; ++i) accD[mt][i] = aD[mt][i];
  } else {
    pass_crs<4, 3, 2, 2, 256>(sm, OFF_X, OFF_Y, wr + OFF0 + 8192, wr + OFF0,
                              b1_0 + r * 64, T1p1, T0p1, lane, cp);
    f32x4 aD[1][2];
    conv_pp<4, 2, 1, 1, 256>(sm, OFF_X, wr + OFF1, wr + OFF1, down_b + r * 64,
                             TDp2, TDp2, lane, cp, aD);
#pragma unroll
    for (int i = 0; i < 2; ++i) accD[0][i] = aD[0][i];
  }
  __syncthreads();

  // ---- p3: H0 = relu(relu(conv2_0(Y0)) + down) ----
  if (h == 0) {
    f32x4 a[2][2];
    conv_pp<2, 0, 2, 2, 128>(sm, OFF_Y, wr + OFF2 + 4096, wr + OFF2, b2_0 + r * 64,
                             T1p3, T0p3, lane, cp, a);
#pragma unroll
    for (int mt = 0; mt < 2; ++mt)
#pragma unroll
      for (int i = 0; i < 2; ++i)
#pragma unroll
        for (int g = 0; g < 4; ++g)
          a[mt][i][g] = fmaxf(fmaxf(a[mt][i][g], 0.f) + accD[mt][i][g], 0.f);
    store_pp<0, 2>(sm, OFF_H0, lane, cp, a);
  } else {
    f32x4 a[1][2];
    conv_pp<2, 2, 1, 2, 128>(sm, OFF_Y, wr + OFF2 + 4096, wr + OFF2, b2_0 + r * 64,
                             T1p3, T0p3, lane, cp, a);
#pragma unroll
    for (int i = 0; i < 2; ++i)
#pragma unroll
      for (int g = 0; g < 4; ++g)
        a[0][i][g] = fmaxf(fmaxf(a[0][i][g], 0.f) + accD[0][i][g], 0.f);
    store_pp<2, 1>(sm, OFF_H0, lane, cp, a);
  }
  __syncthreads();

  // ---- level 1 (d=2) ----
  {
    const short* wb = wr + OFFL0;
    if (h == 0)
      pass_crs<2, 0, 2, 2, 128>(sm, OFF_H0, OFF_Y, wb + 4096, wb,
                                b1s + (r * 7 + 0) * 64, T1L1a, T0L1a, lane, cp);
    else
      pass_crs<2, 2, 1, 2, 128>(sm, OFF_H0, OFF_Y, wb + 4096, wb,
                                b1s + (r * 7 + 0) * 64, T1L1a, T0L1a, lane, cp);
  }
  __syncthreads();
  {
    const short* wb = wr + OFFL0 + 8192;
    if (h == 0)
      pass_crr<2, 0, 1, 2, 128>(sm, OFF_Y, OFF_H0, OFF_H1, wb + 4096, wb,
                                b2s + (r * 7 + 0) * 64, T1L1b, T0L1b, RL1b, lane, cp);
    else
      pass_crr<2, 1, 1, 2, 128>(sm, OFF_Y, OFF_H0, OFF_H1, wb + 4096, wb,
                                b2s + (r * 7 + 0) * 64, T1L1b, T0L1b, RL1b, lane, cp);
  }
  __syncthreads();

  // ---- level 2 (d=4) ----
  {
    const short* wb = wr + OFFL0 + 16384;
    if (h == 0)
      pass_crs<2, 0, 1, 2, 128>(sm, OFF_H1, OFF_Y, wb + 4096, wb,
                                b1s + (r * 7 + 1) * 64, T1L2a, T0L2a, lane, cp);
    else
      pass_crs<2, 1, 1, 2, 128>(sm, OFF_H1, OFF_Y, wb + 4096, wb,
                                b1s + (r * 7 + 1) * 64, T1L2a, T0L2a, lane, cp);
  }
  __syncthreads();
  {
    const short* wb = wr + OFFL0 + 16384 + 8192;   // NMT=1: dup across h
    pass_crr<2, 0, 1, 2, 128>(sm, OFF_Y, OFF_H1, OFF_H2, wb + 4096, wb,
                              b2s + (r * 7 + 1) * 64, T1L2b, T0L2b, RL2b, lane, cp);
  }
  __syncthreads();

  // ---- level 3 (d=8): dup across h ----
  {
    const short* wb = wr + OFFL0 + 32768;
    pass_crs<2, 0, 1, 2, 128>(sm, OFF_H2, OFF_Y, wb + 4096, wb,
                              b1s + (r * 7 + 2) * 64, T1L3a, T0L3a, lane, cp);
  }
  __syncthreads();
  {
    const short* wb = wr + OFFL0 + 32768 + 8192;
    pass_crr<2, 0, 1, 2, 128>(sm, OFF_Y, OFF_H2, OFF_H3, wb + 4096, wb,
                              b2s + (r * 7 + 2) * 64, T1L3b, T0L3b, RL3b, lane, cp);
  }
  __syncthreads();

  // ---- levels 4..7 (single slot t=9): dup across h ----
  f32x4 hfin[2];
#pragma unroll 1
  for (int li = 0; li < 4; ++li) {
    const short* base = wr + OFFL0 + (3 + li) * 16384;
    const int prevOff = OFF_H3 + li * 1024;
    {
      f32x4 a[1][2];
      conv_pp<2, 0, 1, 1, 128>(sm, prevOff, base + 4096, base + 4096,
                               b1s + (r * 7 + 3 + li) * 64, TA, TA, lane, cp, a);
      RELU_PP(a, 1)
      store_pp<0, 1>(sm, OFF_Y, lane, cp, a);
    }
    __syncthreads();
    {
      f32x4 a[1][2];
      conv_pp<2, 0, 1, 1, 128>(sm, OFF_Y, base + 8192 + 4096, base + 8192 + 4096,
                               b2s + (r * 7 + 3 + li) * 64, TA, TA, lane, cp, a);
      resid_pp<0, 1>(sm, prevOff, TA, lane, cp, a);
      if (li < 3) store_pp<0, 1>(sm, prevOff + 1024, lane, cp, a);
      hfin[0] = a[0][0];
      hfin[1] = a[0][1];
    }
    __syncthreads();
  }

  // ---- epilogue (h==0 waves only): mask + reduce over 8 seqs ----
  if (h == 0) {
    float mk = ((lane & 15) < 8) ? mkv[lane & 7] : 0.f;
#pragma unroll
    for (int i = 0; i < 2; ++i) {
      float s0 = hfin[i][0] * mk, s1 = hfin[i][1] * mk;
      float s2 = hfin[i][2] * mk, s3 = hfin[i][3] * mk;
#pragma unroll
      for (int m2 = 1; m2 <= 4; m2 <<= 1) {
        s0 += __shfl_xor(s0, m2);
        s1 += __shfl_xor(s1, m2);
        s2 += __shfl_xor(s2, m2);
        s3 += __shfl_xor(s3, m2);
      }
      if ((lane & 15) == 0) {
        int ct = 2 * cp + i;
        int base = ((r * Bb + b) * 8 + chunk) * 64 + ct * 16 + (lane >> 4) * 4;
        P[base + 0] = s0;
        P[base + 1] = s1;
        P[base + 2] = s2;
        P[base + 3] = s3;
      }
    }
  }
}

// ---------------------------------------------------------------------------
// out[b][i] = sum_r sum_c (sum_p P[r][b][p][c]) * rel_w[r][c][i]
// ---------------------------------------------------------------------------
extern "C" __global__ void reduce_kernel(const float* __restrict__ P,
                                         const float* __restrict__ rel_w,
                                         float* __restrict__ out) {
  __shared__ float Sl[Rr * Cc];
  int b = blockIdx.x, i = threadIdx.x;
  for (int idx = i; idx < Rr * Cc; idx += 64) {
    int rr = idx >> 6, cc = idx & 63;
    float s = 0.f;
    for (int p = 0; p < 8; ++p) s += P[((rr * Bb + b) * 8 + p) * 64 + cc];
    Sl[idx] = s;
  }
  __syncthreads();
  float acc = 0.f;
  for (int r = 0; r < Rr; ++r)
#pragma unroll
    for (int cc = 0; cc < 64; ++cc)
      acc += Sl[r * Cc + cc] * rel_w[(r * Cc + cc) * Ii + i];
  out[b * Ii + i] = acc;
}

// ---------------------------------------------------------------------------
extern "C" void kernel_launch(void* const* d_in, const int* in_sizes, int n_in,
                              void* d_out, int out_size, void* d_ws, size_t ws_size,
                              hipStream_t stream) {
  const float* emb    = (const float*)d_in[0];
  const float* w1_0   = (const float*)d_in[1];
  const float* b1_0   = (const float*)d_in[2];
  const float* w2_0   = (const float*)d_in[3];
  const float* b2_0   = (const float*)d_in[4];
  const float* down_w = (const float*)d_in[5];
  const float* down_b = (const float*)d_in[6];
  const float* w1s    = (const float*)d_in[7];
  const float* b1s    = (const float*)d_in[8];
  const float* w2s    = (const float*)d_in[9];
  const float* b2s    = (const float*)d_in[10];
  const float* rel_w  = (const float*)d_in[11];
  const int* align_   = (const int*)d_in[12];
  const int* nidx     = (const int*)d_in[13];
  const int* nmask    = (const int*)d_in[14];

  float* P  = (float*)d_ws;                       // 4*64*8*64 f32 = 512 KB
  short* Wf = (short*)((char*)d_ws + 524288);     // 589824 bf16 = 1.15 MB

  prep_kernel<<<768, 256, 0, stream>>>(w1_0, w2_0, down_w, w1s, w2s, Wf);
  tcn_mfma<<<2048, 256, 0, stream>>>(emb, align_, nidx, nmask, b1_0, b2_0, down_b,
                                     b1s, b2s, Wf, P);
  reduce_kernel<<<Bb, Cc, 0, stream>>>(P, rel_w, (float*)d_out);
}